// Round 12
// baseline (206.013 us; speedup 1.0000x reference)
//
#include <hip/hip_runtime.h>
#include <hip/hip_bf16.h>

// GCN 2-layer forward. Bucketed CSR build, descending-degree schedule,
// 4x32-feature slice-major h1s (64 B line-aligned slice rows, XCD-pair-pinned),
// unroll-8 gathers, partial GEMM2 per slice + reduce.

#define D1 128
#define BSH 9                 // 512 nodes per bucket
#define BSZ (1 << BSH)
#define CHA 4096              // edges per block in pass A

typedef __attribute__((ext_vector_type(8))) short short8;
typedef __attribute__((ext_vector_type(4))) float floatx4;

__device__ __forceinline__ unsigned short f2bf(float f) {
    unsigned u = __float_as_uint(f);
    u += 0x7fff + ((u >> 16) & 1);         // RNE to bf16
    return (unsigned short)(u >> 16);
}
__device__ __forceinline__ float bflo(unsigned u) { return __uint_as_float(u << 16); }
__device__ __forceinline__ float bfhi(unsigned u) { return __uint_as_float(u & 0xffff0000u); }

// ---------------- init: zero bucket counts + convert W1 -> W1^T bf16 ----------------
__global__ void k_init(const float* __restrict__ W1, unsigned short* __restrict__ W1t,
                       int* __restrict__ bcount) {
    int i = blockIdx.x * 256 + threadIdx.x;
    if (i < 256) bcount[i] = 0;
    if (i < D1 * D1) {
        int c = i >> 7, k = i & 127;
        W1t[c * D1 + k] = f2bf(W1[k * D1 + c]);
    }
}

// ---------------- bucket-level histogram ----------------
__global__ __launch_bounds__(256) void k_bcount(const int* __restrict__ dst,
                                                int* __restrict__ bcount,
                                                int E, int nbuck) {
    __shared__ int h[256];
    int t = threadIdx.x;
    h[t] = 0;
    __syncthreads();
    for (int i = blockIdx.x * 256 + t; i < E; i += gridDim.x * 256)
        atomicAdd(&h[dst[i] >> BSH], 1);
    __syncthreads();
    if (t < nbuck && h[t]) atomicAdd(&bcount[t], h[t]);
}

// ---------------- 1-block scan of bucket counts -> bbase, bcur ----------------
__global__ __launch_bounds__(256) void k_bscan(const int* __restrict__ bcount,
                                               int* __restrict__ bbase,
                                               int* __restrict__ bcur,
                                               int* __restrict__ rowptr,
                                               int nbuck, int N, int E) {
    __shared__ int sd[256];
    int t = threadIdx.x;
    int v = (t < nbuck) ? bcount[t] : 0;
    sd[t] = v;
    __syncthreads();
    for (int off = 1; off < 256; off <<= 1) {
        int x = (t >= off) ? sd[t - off] : 0;
        __syncthreads();
        sd[t] += x;
        __syncthreads();
    }
    int excl = sd[t] - v;
    if (t < nbuck) { bbase[t] = excl; bcur[t] = excl; }
    if (t == 0) {
        bbase[nbuck] = E;
        rowptr[N] = E;
    }
}

// ---------------- pass A: bucket edges, packed = src<<9 | (dst&511) ----------------
__global__ __launch_bounds__(256) void k_binA(
    const int* __restrict__ src, const int* __restrict__ dst,
    int* __restrict__ bcur, unsigned* __restrict__ packed, int E, int nbuck)
{
    __shared__ int hist[256];
    __shared__ int cur[256];
    const int t = threadIdx.x;
    const int e0 = blockIdx.x * CHA;
    const int e1 = min(e0 + CHA, E);

    for (int i = t; i < nbuck; i += 256) hist[i] = 0;
    __syncthreads();
    for (int i = e0 + t; i < e1; i += 256)
        atomicAdd(&hist[dst[i] >> BSH], 1);
    __syncthreads();
    for (int i = t; i < nbuck; i += 256)
        cur[i] = (hist[i] > 0) ? atomicAdd(&bcur[i], hist[i]) : 0;
    __syncthreads();
    for (int i = e0 + t; i < e1; i += 256) {
        int d = dst[i];
        int b = d >> BSH;
        int pos = atomicAdd(&cur[b], 1);
        packed[pos] = ((unsigned)src[i] << BSH) | (unsigned)(d & (BSZ - 1));
    }
}

// ---------------- pass B: per-bucket hist/scan/rowptr/dinv/esrc
//                  + DESCENDING-degree schedule (order) ----------------
__global__ __launch_bounds__(512) void k_binB(
    const int* __restrict__ bbase, const unsigned* __restrict__ packed,
    int* __restrict__ rowptr, float* __restrict__ dinv,
    int* __restrict__ esrc, int* __restrict__ order, int N)
{
    __shared__ int lh[BSZ];
    __shared__ int sd[BSZ];
    __shared__ int lcur[BSZ];
    __shared__ int dbin[64];
    __shared__ int dcur[64];

    const int t = threadIdx.x;
    const int s = blockIdx.x << BSH;
    const int n = min(BSZ, N - s);
    const int base = bbase[blockIdx.x];
    const int cnt = bbase[blockIdx.x + 1] - base;

    lh[t] = 0;
    if (t < 64) dbin[t] = 0;
    __syncthreads();
    for (int i = t; i < cnt; i += 512)
        atomicAdd(&lh[packed[base + i] & (BSZ - 1)], 1);
    __syncthreads();

    sd[t] = lh[t];
    __syncthreads();
    for (int off = 1; off < BSZ; off <<= 1) {
        int x = (t >= off) ? sd[t - off] : 0;
        __syncthreads();
        sd[t] += x;
        __syncthreads();
    }
    int excl = sd[t] - lh[t];
    if (t < n) {
        rowptr[s + t] = base + excl;
        dinv[s + t] = rsqrtf(1.0f + (float)lh[t]);
        atomicAdd(&dbin[63 - min(lh[t], 63)], 1);   // reversed key -> descending
    }
    lcur[t] = excl;
    __syncthreads();

    for (int i = t; i < cnt; i += 512) {
        unsigned p = packed[base + i];
        int ld = (int)(p & (BSZ - 1));
        int pos = atomicAdd(&lcur[ld], 1);
        esrc[base + pos] = (int)(p >> BSH);
    }

    __syncthreads();
    if (t < 64) sd[t] = dbin[t];
    __syncthreads();
    for (int off = 1; off < 64; off <<= 1) {
        int x = (t >= off && t < 64) ? sd[t - off] : 0;
        __syncthreads();
        if (t < 64) sd[t] += x;
        __syncthreads();
    }
    if (t < 64) dcur[t] = sd[t] - dbin[t];
    __syncthreads();
    if (t < n) {
        int b = 63 - min(lh[t], 63);
        int pos = atomicAdd(&dcur[b], 1);
        order[s + pos] = s + t;
    }
}

// ---------------- GEMM1 (MFMA): h1s[slice][row][32] = bf16 of (x@W1)*dinv -------
// slice = feature/32; slice row = 64 B (one cache line).
#define BMM 64
__global__ __launch_bounds__(256) void k_gemm1(
    const float* __restrict__ x, const unsigned short* __restrict__ W1t,
    const float* __restrict__ dinv, unsigned short* __restrict__ h1s, int N)
{
    __shared__ unsigned short Xs[BMM][136];
    __shared__ unsigned short Ws[D1][136];

    const int t = threadIdx.x;
    const int row0 = blockIdx.x * BMM;

#pragma unroll
    for (int i = 0; i < 8; ++i) {
        int idx = t + 256 * i;
        int r = idx >> 4, c8 = idx & 15;
        short8 v = ((const short8*)W1t)[r * 16 + c8];
        *(short8*)&Ws[r][c8 * 8] = v;
    }
#pragma unroll
    for (int i = 0; i < 4; ++i) {
        int idx = t + 256 * i;
        int r = idx >> 4, c8 = idx & 15;
        int row = row0 + r;
        short8 v8 = (short8)0;
        if (row < N) {
            const float* p = x + (size_t)row * D1 + c8 * 8;
            float4 f0 = *(const float4*)p;
            float4 f1 = *(const float4*)(p + 4);
            v8[0] = (short)f2bf(f0.x); v8[1] = (short)f2bf(f0.y);
            v8[2] = (short)f2bf(f0.z); v8[3] = (short)f2bf(f0.w);
            v8[4] = (short)f2bf(f1.x); v8[5] = (short)f2bf(f1.y);
            v8[6] = (short)f2bf(f1.z); v8[7] = (short)f2bf(f1.w);
        }
        *(short8*)&Xs[r][c8 * 8] = v8;
    }
    __syncthreads();

    const int w = t >> 6;
    const int l = t & 63;
    const int m = l & 15;
    const int q = l >> 4;

    floatx4 acc[8];
#pragma unroll
    for (int c = 0; c < 8; ++c) acc[c] = (floatx4)0.0f;

#pragma unroll
    for (int ks = 0; ks < 4; ++ks) {
        short8 a = *(const short8*)&Xs[16 * w + m][ks * 32 + q * 8];
#pragma unroll
        for (int c = 0; c < 8; ++c) {
            short8 b = *(const short8*)&Ws[c * 16 + m][ks * 32 + q * 8];
            acc[c] = __builtin_amdgcn_mfma_f32_16x16x32_bf16(a, b, acc[c], 0, 0, 0);
        }
    }

    // store slice-major-32: feature f = c*16+m -> slice c>>1, offset (c&1)*16+m
#pragma unroll
    for (int r = 0; r < 4; ++r) {
        int row = row0 + 16 * w + q * 4 + r;
        if (row >= N) continue;
        float di = dinv[row];
#pragma unroll
        for (int c = 0; c < 8; ++c)
            h1s[((size_t)(c >> 1) * N + row) * 32 + (c & 1) * 16 + m] = f2bf(acc[c][r] * di);
    }
}

#define ACC8(A, v) \
    A[0] += bflo(v.x); A[1] += bfhi(v.x); \
    A[2] += bflo(v.y); A[3] += bfhi(v.y); \
    A[4] += bflo(v.z); A[5] += bfhi(v.z); \
    A[6] += bflo(v.w); A[7] += bfhi(v.w);

// ---------------- sliced agg + relu + bias + partial GEMM2, unroll-8 ------
// slice = blockIdx&3 (XCD-pair-pinned). 4 lanes/node, uint4 (8 bf16)/lane;
// one edge-slice gather = 4 lanes x 16 B = one full 64 B line.
__global__ __launch_bounds__(256) void k_agg1(
    const int* __restrict__ rowptr, const int* __restrict__ esrc,
    const int* __restrict__ order,
    const float* __restrict__ dinv, const unsigned short* __restrict__ h1s,
    const float* __restrict__ b1, const float* __restrict__ W2,
    float2* __restrict__ hp, int N)
{
    const int slice = blockIdx.x & 3;
    const int chunk = blockIdx.x >> 2;
    const int t = threadIdx.x;
    const int grp = chunk * 64 + (t >> 2);
    if (grp >= N) return;
    const int lane = t & 3;
    const int node = order[grp];

    const uint4* hv = (const uint4*)h1s + (size_t)slice * N * 4;  // 4 uint4/row

    uint4 u = hv[(size_t)node * 4 + lane];
    float accA[8], accB[8];
    accA[0] = bflo(u.x); accA[1] = bfhi(u.x);
    accA[2] = bflo(u.y); accA[3] = bfhi(u.y);
    accA[4] = bflo(u.z); accA[5] = bfhi(u.z);
    accA[6] = bflo(u.w); accA[7] = bfhi(u.w);
#pragma unroll
    for (int j = 0; j < 8; ++j) accB[j] = 0.f;

    int beg = rowptr[node], end = rowptr[node + 1];
    int e = beg;
    for (; e + 7 < end; e += 8) {
        int s0 = esrc[e],     s1 = esrc[e + 1], s2 = esrc[e + 2], s3 = esrc[e + 3];
        int s4 = esrc[e + 4], s5 = esrc[e + 5], s6 = esrc[e + 6], s7 = esrc[e + 7];
        uint4 v0 = hv[(size_t)s0 * 4 + lane];
        uint4 v1 = hv[(size_t)s1 * 4 + lane];
        uint4 v2 = hv[(size_t)s2 * 4 + lane];
        uint4 v3 = hv[(size_t)s3 * 4 + lane];
        uint4 v4 = hv[(size_t)s4 * 4 + lane];
        uint4 v5 = hv[(size_t)s5 * 4 + lane];
        uint4 v6 = hv[(size_t)s6 * 4 + lane];
        uint4 v7 = hv[(size_t)s7 * 4 + lane];
        ACC8(accA, v0) ACC8(accB, v1) ACC8(accA, v2) ACC8(accB, v3)
        ACC8(accA, v4) ACC8(accB, v5) ACC8(accA, v6) ACC8(accB, v7)
    }
    if (e + 3 < end) {
        int s0 = esrc[e], s1 = esrc[e + 1], s2 = esrc[e + 2], s3 = esrc[e + 3];
        uint4 v0 = hv[(size_t)s0 * 4 + lane];
        uint4 v1 = hv[(size_t)s1 * 4 + lane];
        uint4 v2 = hv[(size_t)s2 * 4 + lane];
        uint4 v3 = hv[(size_t)s3 * 4 + lane];
        ACC8(accA, v0) ACC8(accB, v1) ACC8(accA, v2) ACC8(accB, v3)
        e += 4;
    }
    for (; e < end; ++e) {
        uint4 v = hv[(size_t)esrc[e] * 4 + lane];
        ACC8(accB, v)
    }

    float di = dinv[node];
    const int f0 = slice * 32 + lane * 8;     // first feature of this lane
    const float4* b1v = (const float4*)b1;
    float4 bbA = b1v[f0 >> 2];
    float4 bbB = b1v[(f0 >> 2) + 1];
    float a[8];
    a[0] = fmaxf((accA[0] + accB[0]) * di + bbA.x, 0.f);
    a[1] = fmaxf((accA[1] + accB[1]) * di + bbA.y, 0.f);
    a[2] = fmaxf((accA[2] + accB[2]) * di + bbA.z, 0.f);
    a[3] = fmaxf((accA[3] + accB[3]) * di + bbA.w, 0.f);
    a[4] = fmaxf((accA[4] + accB[4]) * di + bbB.x, 0.f);
    a[5] = fmaxf((accA[5] + accB[5]) * di + bbB.y, 0.f);
    a[6] = fmaxf((accA[6] + accB[6]) * di + bbB.z, 0.f);
    a[7] = fmaxf((accA[7] + accB[7]) * di + bbB.w, 0.f);

    // partial GEMM2 over features f0..f0+7
    const float4* W2v = (const float4*)W2;
    float p0 = 0.f, p1 = 0.f;
#pragma unroll
    for (int j2 = 0; j2 < 4; ++j2) {
        float4 wv = W2v[(f0 >> 1) + j2];
        p0 += a[j2 * 2] * wv.x + a[j2 * 2 + 1] * wv.z;
        p1 += a[j2 * 2] * wv.y + a[j2 * 2 + 1] * wv.w;
    }
    p0 += __shfl_xor(p0, 1); p1 += __shfl_xor(p1, 1);
    p0 += __shfl_xor(p0, 2); p1 += __shfl_xor(p1, 2);
    if (lane == 0) hp[(size_t)slice * N + grp] = make_float2(p0, p1);
}

// ---------------- reduce 4 slice partials -> h2s (stores h2*dinv) ----------------
__global__ void k_h2red(const float2* __restrict__ hp, const int* __restrict__ order,
                        const float* __restrict__ dinv, float* __restrict__ h2s, int N)
{
    int g = blockIdx.x * 256 + threadIdx.x;
    if (g >= N) return;
    float p0 = 0.f, p1 = 0.f;
#pragma unroll
    for (int s = 0; s < 4; ++s) {
        float2 v = hp[(size_t)s * N + g];
        p0 += v.x; p1 += v.y;
    }
    int node = order[g];
    float di = dinv[node];
    ((float2*)h2s)[node] = make_float2(p0 * di, p1 * di);
}

// ---------------- gather layer 2: out = dinv_i*(h2s_i + sum h2s_src) + b2 -------
__global__ void k_gather2(const int* __restrict__ rowptr, const int* __restrict__ esrc,
                          const float* __restrict__ h2s, const float* __restrict__ dinv,
                          const float* __restrict__ b2, float* __restrict__ out, int N)
{
    int i = blockIdx.x * 256 + threadIdx.x;
    if (i >= N) return;
    const float2* h2v = (const float2*)h2s;
    float2 h = h2v[i];
    float o0a = h.x, o1a = h.y;
    float o0b = 0.f, o1b = 0.f;
    int beg = rowptr[i], end = rowptr[i + 1];
    int e = beg;
    for (; e + 7 < end; e += 8) {
        int s0 = esrc[e],     s1 = esrc[e + 1], s2 = esrc[e + 2], s3 = esrc[e + 3];
        int s4 = esrc[e + 4], s5 = esrc[e + 5], s6 = esrc[e + 6], s7 = esrc[e + 7];
        float2 v0 = h2v[s0], v1 = h2v[s1], v2 = h2v[s2], v3 = h2v[s3];
        float2 v4 = h2v[s4], v5 = h2v[s5], v6 = h2v[s6], v7 = h2v[s7];
        o0a += v0.x + v2.x + v4.x + v6.x; o1a += v0.y + v2.y + v4.y + v6.y;
        o0b += v1.x + v3.x + v5.x + v7.x; o1b += v1.y + v3.y + v5.y + v7.y;
    }
    for (; e < end; ++e) {
        float2 v = h2v[esrc[e]];
        o0b += v.x; o1b += v.y;
    }
    float di = dinv[i];
    ((float2*)out)[i] = make_float2((o0a + o0b) * di + b2[0], (o1a + o1b) * di + b2[1]);
}

extern "C" void kernel_launch(void* const* d_in, const int* in_sizes, int n_in,
                              void* d_out, int out_size, void* d_ws, size_t ws_size,
                              hipStream_t stream)
{
    const float* x  = (const float*)d_in[0];
    const int*   ei = (const int*)d_in[1];
    const float* W1 = (const float*)d_in[2];
    const float* b1 = (const float*)d_in[3];
    const float* W2 = (const float*)d_in[4];
    const float* b2 = (const float*)d_in[5];
    float* out = (float*)d_out;

    const int N = in_sizes[0] / D1;
    const int E = in_sizes[1] / 2;
    const int* src = ei;
    const int* dst = ei + E;

    char* w = (char*)d_ws;
    auto alloc = [&](size_t bytes) -> char* {
        char* r = w;
        w += (bytes + 63) & ~(size_t)63;   // 64 B-align every region
        return r;
    };
    unsigned short* h1s = (unsigned short*)alloc((size_t)N * D1 * 2);  // slice-major-32
    unsigned short* W1t = (unsigned short*)alloc((size_t)D1 * D1 * 2);
    float* h2s    = (float*)alloc((size_t)N * 2 * 4);
    float2* hp    = (float2*)alloc((size_t)N * 4 * 8);
    float* dinv   = (float*)alloc((size_t)N * 4);
    int*   rowptr = (int*)alloc((size_t)(N + 4) * 4);
    int*   order  = (int*)alloc((size_t)N * 4);
    int*   bcount = (int*)alloc(256 * 4);
    int*   bbase  = (int*)alloc(260 * 4);
    int*   bcur   = (int*)alloc(256 * 4);
    unsigned* packed = (unsigned*)alloc((size_t)E * 4);
    int*   esrc   = (int*)alloc((size_t)E * 4);

    const int nbuck = (N + BSZ - 1) >> BSH;

    k_init  <<<(D1 * D1 + 255) / 256, 256, 0, stream>>>(W1, W1t, bcount);
    k_bcount<<<256, 256, 0, stream>>>(dst, bcount, E, nbuck);
    k_bscan <<<1, 256, 0, stream>>>(bcount, bbase, bcur, rowptr, nbuck, N, E);
    k_binA  <<<(E + CHA - 1) / CHA, 256, 0, stream>>>(src, dst, bcur, packed, E, nbuck);
    k_binB  <<<nbuck, 512, 0, stream>>>(bbase, packed, rowptr, dinv, esrc, order, N);

    k_gemm1<<<(N + BMM - 1) / BMM, 256, 0, stream>>>(x, W1t, dinv, h1s, N);

    const int nchunk = (N + 63) / 64;
    k_agg1 <<<nchunk * 4, 256, 0, stream>>>(rowptr, esrc, order, dinv, h1s, b1, W2, hp, N);
    k_h2red<<<(N + 255) / 256, 256, 0, stream>>>(hp, order, dinv, h2s, N);

    k_gather2<<<(N + 255) / 256, 256, 0, stream>>>(rowptr, esrc, h2s, dinv, b2, out, N);
}

// Round 13
// 196.938 us; speedup vs baseline: 1.0461x; 1.0461x over previous
//
#include <hip/hip_runtime.h>
#include <hip/hip_bf16.h>

// GCN 2-layer forward. Bucketed CSR build, descending-degree schedule,
// node-major h1s, unroll-8 gathers, gemm1 with LDS-transposed coalesced epilogue.

#define D1 128
#define BSH 9                 // 512 nodes per bucket
#define BSZ (1 << BSH)
#define CHA 4096              // edges per block in pass A

typedef __attribute__((ext_vector_type(8))) short short8;
typedef __attribute__((ext_vector_type(4))) float floatx4;

__device__ __forceinline__ unsigned short f2bf(float f) {
    unsigned u = __float_as_uint(f);
    u += 0x7fff + ((u >> 16) & 1);         // RNE to bf16
    return (unsigned short)(u >> 16);
}
__device__ __forceinline__ float bflo(unsigned u) { return __uint_as_float(u << 16); }
__device__ __forceinline__ float bfhi(unsigned u) { return __uint_as_float(u & 0xffff0000u); }

// ---------------- init: zero bucket counts + convert W1 -> W1^T bf16 ----------------
__global__ void k_init(const float* __restrict__ W1, unsigned short* __restrict__ W1t,
                       int* __restrict__ bcount) {
    int i = blockIdx.x * 256 + threadIdx.x;
    if (i < 256) bcount[i] = 0;
    if (i < D1 * D1) {
        int c = i >> 7, k = i & 127;
        W1t[c * D1 + k] = f2bf(W1[k * D1 + c]);
    }
}

// ---------------- bucket-level histogram ----------------
__global__ __launch_bounds__(256) void k_bcount(const int* __restrict__ dst,
                                                int* __restrict__ bcount,
                                                int E, int nbuck) {
    __shared__ int h[256];
    int t = threadIdx.x;
    h[t] = 0;
    __syncthreads();
    for (int i = blockIdx.x * 256 + t; i < E; i += gridDim.x * 256)
        atomicAdd(&h[dst[i] >> BSH], 1);
    __syncthreads();
    if (t < nbuck && h[t]) atomicAdd(&bcount[t], h[t]);
}

// ---------------- 1-block scan of bucket counts -> bbase, bcur ----------------
__global__ __launch_bounds__(256) void k_bscan(const int* __restrict__ bcount,
                                               int* __restrict__ bbase,
                                               int* __restrict__ bcur,
                                               int* __restrict__ rowptr,
                                               int nbuck, int N, int E) {
    __shared__ int sd[256];
    int t = threadIdx.x;
    int v = (t < nbuck) ? bcount[t] : 0;
    sd[t] = v;
    __syncthreads();
    for (int off = 1; off < 256; off <<= 1) {
        int x = (t >= off) ? sd[t - off] : 0;
        __syncthreads();
        sd[t] += x;
        __syncthreads();
    }
    int excl = sd[t] - v;
    if (t < nbuck) { bbase[t] = excl; bcur[t] = excl; }
    if (t == 0) {
        bbase[nbuck] = E;
        rowptr[N] = E;
    }
}

// ---------------- pass A: bucket edges, packed = src<<9 | (dst&511) ----------------
__global__ __launch_bounds__(256) void k_binA(
    const int* __restrict__ src, const int* __restrict__ dst,
    int* __restrict__ bcur, unsigned* __restrict__ packed, int E, int nbuck)
{
    __shared__ int hist[256];
    __shared__ int cur[256];
    const int t = threadIdx.x;
    const int e0 = blockIdx.x * CHA;
    const int e1 = min(e0 + CHA, E);

    for (int i = t; i < nbuck; i += 256) hist[i] = 0;
    __syncthreads();
    for (int i = e0 + t; i < e1; i += 256)
        atomicAdd(&hist[dst[i] >> BSH], 1);
    __syncthreads();
    for (int i = t; i < nbuck; i += 256)
        cur[i] = (hist[i] > 0) ? atomicAdd(&bcur[i], hist[i]) : 0;
    __syncthreads();
    for (int i = e0 + t; i < e1; i += 256) {
        int d = dst[i];
        int b = d >> BSH;
        int pos = atomicAdd(&cur[b], 1);
        packed[pos] = ((unsigned)src[i] << BSH) | (unsigned)(d & (BSZ - 1));
    }
}

// ---------------- pass B: per-bucket hist/scan/rowptr/dinv/esrc
//                  + DESCENDING-degree schedule (order) ----------------
__global__ __launch_bounds__(512) void k_binB(
    const int* __restrict__ bbase, const unsigned* __restrict__ packed,
    int* __restrict__ rowptr, float* __restrict__ dinv,
    int* __restrict__ esrc, int* __restrict__ order, int N)
{
    __shared__ int lh[BSZ];
    __shared__ int sd[BSZ];
    __shared__ int lcur[BSZ];
    __shared__ int dbin[64];
    __shared__ int dcur[64];

    const int t = threadIdx.x;
    const int s = blockIdx.x << BSH;
    const int n = min(BSZ, N - s);
    const int base = bbase[blockIdx.x];
    const int cnt = bbase[blockIdx.x + 1] - base;

    lh[t] = 0;
    if (t < 64) dbin[t] = 0;
    __syncthreads();
    for (int i = t; i < cnt; i += 512)
        atomicAdd(&lh[packed[base + i] & (BSZ - 1)], 1);
    __syncthreads();

    sd[t] = lh[t];
    __syncthreads();
    for (int off = 1; off < BSZ; off <<= 1) {
        int x = (t >= off) ? sd[t - off] : 0;
        __syncthreads();
        sd[t] += x;
        __syncthreads();
    }
    int excl = sd[t] - lh[t];
    if (t < n) {
        rowptr[s + t] = base + excl;
        dinv[s + t] = rsqrtf(1.0f + (float)lh[t]);
        atomicAdd(&dbin[63 - min(lh[t], 63)], 1);   // reversed key -> descending
    }
    lcur[t] = excl;
    __syncthreads();

    for (int i = t; i < cnt; i += 512) {
        unsigned p = packed[base + i];
        int ld = (int)(p & (BSZ - 1));
        int pos = atomicAdd(&lcur[ld], 1);
        esrc[base + pos] = (int)(p >> BSH);
    }

    __syncthreads();
    if (t < 64) sd[t] = dbin[t];
    __syncthreads();
    for (int off = 1; off < 64; off <<= 1) {
        int x = (t >= off && t < 64) ? sd[t - off] : 0;
        __syncthreads();
        if (t < 64) sd[t] += x;
        __syncthreads();
    }
    if (t < 64) dcur[t] = sd[t] - dbin[t];
    __syncthreads();
    if (t < n) {
        int b = 63 - min(lh[t], 63);
        int pos = atomicAdd(&dcur[b], 1);
        order[s + pos] = s + t;
    }
}

// ---------------- GEMM1 (MFMA): h1s = (bf16(x) @ bf16(W1)) * dinv[row] ----------
// Epilogue transposes D through LDS (reusing Xs) for coalesced 16 B stores.
#define BMM 64
__global__ __launch_bounds__(256) void k_gemm1(
    const float* __restrict__ x, const unsigned short* __restrict__ W1t,
    const float* __restrict__ dinv, unsigned short* __restrict__ h1s, int N)
{
    __shared__ unsigned short Xs[BMM][136];   // staging, then D-tile (stride 136)
    __shared__ unsigned short Ws[D1][136];

    const int t = threadIdx.x;
    const int row0 = blockIdx.x * BMM;

#pragma unroll
    for (int i = 0; i < 8; ++i) {
        int idx = t + 256 * i;
        int r = idx >> 4, c8 = idx & 15;
        short8 v = ((const short8*)W1t)[r * 16 + c8];
        *(short8*)&Ws[r][c8 * 8] = v;
    }
#pragma unroll
    for (int i = 0; i < 4; ++i) {
        int idx = t + 256 * i;
        int r = idx >> 4, c8 = idx & 15;
        int row = row0 + r;
        short8 v8 = (short8)0;
        if (row < N) {
            const float* p = x + (size_t)row * D1 + c8 * 8;
            float4 f0 = *(const float4*)p;
            float4 f1 = *(const float4*)(p + 4);
            v8[0] = (short)f2bf(f0.x); v8[1] = (short)f2bf(f0.y);
            v8[2] = (short)f2bf(f0.z); v8[3] = (short)f2bf(f0.w);
            v8[4] = (short)f2bf(f1.x); v8[5] = (short)f2bf(f1.y);
            v8[6] = (short)f2bf(f1.z); v8[7] = (short)f2bf(f1.w);
        }
        *(short8*)&Xs[r][c8 * 8] = v8;
    }
    __syncthreads();

    const int w = t >> 6;
    const int l = t & 63;
    const int m = l & 15;
    const int q = l >> 4;

    floatx4 acc[8];
#pragma unroll
    for (int c = 0; c < 8; ++c) acc[c] = (floatx4)0.0f;

#pragma unroll
    for (int ks = 0; ks < 4; ++ks) {
        short8 a = *(const short8*)&Xs[16 * w + m][ks * 32 + q * 8];
#pragma unroll
        for (int c = 0; c < 8; ++c) {
            short8 b = *(const short8*)&Ws[c * 16 + m][ks * 32 + q * 8];
            acc[c] = __builtin_amdgcn_mfma_f32_16x16x32_bf16(a, b, acc[c], 0, 0, 0);
        }
    }

    __syncthreads();   // everyone done reading Xs/Ws

    // write D-tile into Xs[row_in_tile][col] (bf16, stride 136), scaled by dinv
#pragma unroll
    for (int r = 0; r < 4; ++r) {
        int rt = 16 * w + q * 4 + r;            // row in tile
        int row = row0 + rt;
        float di = (row < N) ? dinv[row] : 0.f;
#pragma unroll
        for (int c = 0; c < 8; ++c)
            Xs[rt][c * 16 + m] = f2bf(acc[c][r] * di);
    }
    __syncthreads();

    // coalesced store: 64 rows x 16 chunks of 8 bf16 (16 B)
#pragma unroll
    for (int i = 0; i < 4; ++i) {
        int idx = t + 256 * i;
        int r = idx >> 4, c8 = idx & 15;
        int row = row0 + r;
        if (row < N)
            *(short8*)&h1s[(size_t)row * D1 + c8 * 8] = *(const short8*)&Xs[r][c8 * 8];
    }
}

#define ACC8(A, v) \
    A[0] += bflo(v.x); A[1] += bfhi(v.x); \
    A[2] += bflo(v.y); A[3] += bfhi(v.y); \
    A[4] += bflo(v.z); A[5] += bfhi(v.z); \
    A[6] += bflo(v.w); A[7] += bfhi(v.w);

// ---------------- fused: agg(layer1) + relu + bias + GEMM2, unroll-8 ------
__global__ __launch_bounds__(256) void k_agg1_gemm2(
    const int* __restrict__ rowptr, const int* __restrict__ esrc,
    const int* __restrict__ order,
    const float* __restrict__ dinv, const unsigned short* __restrict__ h1s,
    const float* __restrict__ b1, const float* __restrict__ W2,
    float* __restrict__ h2s, int N)
{
    int gid = blockIdx.x * 256 + threadIdx.x;
    int grp = gid >> 4;
    if (grp >= N) return;
    int node = order[grp];
    int lane = gid & 15;

    const uint4* h1v = (const uint4*)h1s;   // 16 uint4 per row

    uint4 u = h1v[(size_t)node * 16 + lane];
    float accA[8], accB[8];
    accA[0] = bflo(u.x); accA[1] = bfhi(u.x);
    accA[2] = bflo(u.y); accA[3] = bfhi(u.y);
    accA[4] = bflo(u.z); accA[5] = bfhi(u.z);
    accA[6] = bflo(u.w); accA[7] = bfhi(u.w);
#pragma unroll
    for (int j = 0; j < 8; ++j) accB[j] = 0.f;

    int beg = rowptr[node], end = rowptr[node + 1];
    int e = beg;
    for (; e + 7 < end; e += 8) {
        int s0 = esrc[e],     s1 = esrc[e + 1], s2 = esrc[e + 2], s3 = esrc[e + 3];
        int s4 = esrc[e + 4], s5 = esrc[e + 5], s6 = esrc[e + 6], s7 = esrc[e + 7];
        uint4 v0 = h1v[(size_t)s0 * 16 + lane];
        uint4 v1 = h1v[(size_t)s1 * 16 + lane];
        uint4 v2 = h1v[(size_t)s2 * 16 + lane];
        uint4 v3 = h1v[(size_t)s3 * 16 + lane];
        uint4 v4 = h1v[(size_t)s4 * 16 + lane];
        uint4 v5 = h1v[(size_t)s5 * 16 + lane];
        uint4 v6 = h1v[(size_t)s6 * 16 + lane];
        uint4 v7 = h1v[(size_t)s7 * 16 + lane];
        ACC8(accA, v0) ACC8(accB, v1) ACC8(accA, v2) ACC8(accB, v3)
        ACC8(accA, v4) ACC8(accB, v5) ACC8(accA, v6) ACC8(accB, v7)
    }
    if (e + 3 < end) {
        int s0 = esrc[e], s1 = esrc[e + 1], s2 = esrc[e + 2], s3 = esrc[e + 3];
        uint4 v0 = h1v[(size_t)s0 * 16 + lane];
        uint4 v1 = h1v[(size_t)s1 * 16 + lane];
        uint4 v2 = h1v[(size_t)s2 * 16 + lane];
        uint4 v3 = h1v[(size_t)s3 * 16 + lane];
        ACC8(accA, v0) ACC8(accB, v1) ACC8(accA, v2) ACC8(accB, v3)
        e += 4;
    }
    for (; e < end; ++e) {
        uint4 v = h1v[(size_t)esrc[e] * 16 + lane];
        ACC8(accB, v)
    }

    float di = dinv[node];
    const float4* b1v = (const float4*)b1;
    float4 bbA = b1v[lane * 2 + 0];
    float4 bbB = b1v[lane * 2 + 1];
    float a[8];
    a[0] = fmaxf((accA[0] + accB[0]) * di + bbA.x, 0.f);
    a[1] = fmaxf((accA[1] + accB[1]) * di + bbA.y, 0.f);
    a[2] = fmaxf((accA[2] + accB[2]) * di + bbA.z, 0.f);
    a[3] = fmaxf((accA[3] + accB[3]) * di + bbA.w, 0.f);
    a[4] = fmaxf((accA[4] + accB[4]) * di + bbB.x, 0.f);
    a[5] = fmaxf((accA[5] + accB[5]) * di + bbB.y, 0.f);
    a[6] = fmaxf((accA[6] + accB[6]) * di + bbB.z, 0.f);
    a[7] = fmaxf((accA[7] + accB[7]) * di + bbB.w, 0.f);

    const float4* W2v = (const float4*)W2;
    float p0 = 0.f, p1 = 0.f;
#pragma unroll
    for (int j2 = 0; j2 < 4; ++j2) {
        float4 wv = W2v[lane * 4 + j2];
        p0 += a[j2 * 2] * wv.x + a[j2 * 2 + 1] * wv.z;
        p1 += a[j2 * 2] * wv.y + a[j2 * 2 + 1] * wv.w;
    }

#pragma unroll
    for (int off = 8; off > 0; off >>= 1) {
        p0 += __shfl_xor(p0, off);
        p1 += __shfl_xor(p1, off);
    }
    if (lane == 0) {
        h2s[(size_t)node * 2 + 0] = p0 * di;   // store h2*dinv
        h2s[(size_t)node * 2 + 1] = p1 * di;
    }
}

// ---------------- gather layer 2: out = dinv_i*(h2s_i + sum h2s_src) + b2 -------
__global__ void k_gather2(const int* __restrict__ rowptr, const int* __restrict__ esrc,
                          const float* __restrict__ h2s, const float* __restrict__ dinv,
                          const float* __restrict__ b2, float* __restrict__ out, int N)
{
    int i = blockIdx.x * 256 + threadIdx.x;
    if (i >= N) return;
    const float2* h2v = (const float2*)h2s;
    float2 h = h2v[i];
    float o0a = h.x, o1a = h.y;
    float o0b = 0.f, o1b = 0.f;
    int beg = rowptr[i], end = rowptr[i + 1];
    int e = beg;
    for (; e + 7 < end; e += 8) {
        int s0 = esrc[e],     s1 = esrc[e + 1], s2 = esrc[e + 2], s3 = esrc[e + 3];
        int s4 = esrc[e + 4], s5 = esrc[e + 5], s6 = esrc[e + 6], s7 = esrc[e + 7];
        float2 v0 = h2v[s0], v1 = h2v[s1], v2 = h2v[s2], v3 = h2v[s3];
        float2 v4 = h2v[s4], v5 = h2v[s5], v6 = h2v[s6], v7 = h2v[s7];
        o0a += v0.x + v2.x + v4.x + v6.x; o1a += v0.y + v2.y + v4.y + v6.y;
        o0b += v1.x + v3.x + v5.x + v7.x; o1b += v1.y + v3.y + v5.y + v7.y;
    }
    for (; e < end; ++e) {
        float2 v = h2v[esrc[e]];
        o0b += v.x; o1b += v.y;
    }
    float di = dinv[i];
    ((float2*)out)[i] = make_float2((o0a + o0b) * di + b2[0], (o1a + o1b) * di + b2[1]);
}

extern "C" void kernel_launch(void* const* d_in, const int* in_sizes, int n_in,
                              void* d_out, int out_size, void* d_ws, size_t ws_size,
                              hipStream_t stream)
{
    const float* x  = (const float*)d_in[0];
    const int*   ei = (const int*)d_in[1];
    const float* W1 = (const float*)d_in[2];
    const float* b1 = (const float*)d_in[3];
    const float* W2 = (const float*)d_in[4];
    const float* b2 = (const float*)d_in[5];
    float* out = (float*)d_out;

    const int N = in_sizes[0] / D1;
    const int E = in_sizes[1] / 2;
    const int* src = ei;
    const int* dst = ei + E;

    char* w = (char*)d_ws;
    auto alloc = [&](size_t bytes) -> char* {
        char* r = w;
        w += (bytes + 63) & ~(size_t)63;
        return r;
    };
    unsigned short* h1s = (unsigned short*)alloc((size_t)N * D1 * 2);
    unsigned short* W1t = (unsigned short*)alloc((size_t)D1 * D1 * 2);
    float* h2s    = (float*)alloc((size_t)N * 2 * 4);
    float* dinv   = (float*)alloc((size_t)N * 4);
    int*   rowptr = (int*)alloc((size_t)(N + 4) * 4);
    int*   order  = (int*)alloc((size_t)N * 4);
    int*   bcount = (int*)alloc(256 * 4);
    int*   bbase  = (int*)alloc(260 * 4);
    int*   bcur   = (int*)alloc(256 * 4);
    unsigned* packed = (unsigned*)alloc((size_t)E * 4);
    int*   esrc   = (int*)alloc((size_t)E * 4);

    const int nbuck = (N + BSZ - 1) >> BSH;

    k_init  <<<(D1 * D1 + 255) / 256, 256, 0, stream>>>(W1, W1t, bcount);
    k_bcount<<<256, 256, 0, stream>>>(dst, bcount, E, nbuck);
    k_bscan <<<1, 256, 0, stream>>>(bcount, bbase, bcur, rowptr, nbuck, N, E);
    k_binA  <<<(E + CHA - 1) / CHA, 256, 0, stream>>>(src, dst, bcur, packed, E, nbuck);
    k_binB  <<<nbuck, 512, 0, stream>>>(bbase, packed, rowptr, dinv, esrc, order, N);

    k_gemm1<<<(N + BMM - 1) / BMM, 256, 0, stream>>>(x, W1t, dinv, h1s, N);

    k_agg1_gemm2<<<(N * 16 + 255) / 256, 256, 0, stream>>>(rowptr, esrc, order, dinv, h1s, b1, W2, h2s, N);

    k_gather2<<<(N + 255) / 256, 256, 0, stream>>>(rowptr, esrc, h2s, dinv, b2, out, N);
}